// Round 14
// baseline (127.463 us; speedup 1.0000x reference)
//
#include <hip/hip_runtime.h>
#include <math.h>

// Chamfer distance, B=4, N=M=8192, fp32.
// Output layout (flat float32): dist1[B*N], dist2[B*M], idx1[B*N] (as float),
// idx2[B*M] (as float).
//
// R13 == R9 verbatim (proven best: 123.5 us total, main 79.2 us).
// Roofline accounting (closed in R12 post-mortem): main's inner loop issues
// ~232 VALU insts per 8-point iter (64 evals: 6 arith + ~0.9 min/update per
// eval, exact-rounding d is irreducible at 6); grid = 8192 waves = exactly
// full chip residency; floor = 49.5 us at 2.4 GHz x (157/103) measured
// sustained-clock derate (learn_hip m07: dense v_fma_f32 = 103 TF full-chip)
// = ~75 us vs 79 measured = 95% of the measured VALU-issue ceiling.
// Escapes tested and closed: t-form screening (R11, guard overhead), packed
// FP32 (R12, scalarized), fused-finalize / single-dispatch (R8/R10, codegen
// poison / fixed tail). Tail ~44 us is harness floor (R9 vs R10 A/B).
//
// Semantics: d = fmaf(dx,dx,fmaf(dy,dy,dz*dz)) — rounding delta ~ulp(d) vs
// reference's ((dx^2+dy^2)+dz^2), ~2300x below typical top-2 gaps -> argmin
// flip-safe (absmax 0 measured on every round since R5). Group-of-8 min tree,
// strict < keeps earliest group; winner resolved by deterministic recompute
// (bitwise-identical d), descending equality scan -> smallest index; u64
// atomicMin of (dist_bits<<32|idx) == (min d, tie -> lower idx) == np.argmin
// first-occurrence, cross-split-safe.

#define QPT 4         // queries per thread
#define BLK 256       // threads per block
#define QPB (QPT*BLK) // queries per block = 1024

__global__ __launch_bounds__(256, 4) void chamfer_main(
    const float* __restrict__ xyz1, const float* __restrict__ xyz2,
    unsigned long long* __restrict__ pp,
    int N, int M, int B, int S, int C)
{
    const int dir = blockIdx.z;          // 0: xyz1->xyz2, 1: xyz2->xyz1
    const float* q = dir ? xyz2 : xyz1;  // query cloud
    const float* r = dir ? xyz1 : xyz2;  // reference cloud
    const int Nq = dir ? M : N;
    const int Nr = dir ? N : M;
    const int b     = blockIdx.y / S;
    const int split = blockIdx.y % S;
    const int base  = split * C;         // this block's ref-index range [base, base+C)

    extern __shared__ float s[];         // C*3 floats

    // cooperative vectorized tile load (C%8==0 -> byte count divisible by 16)
    {
        const float4* gv = (const float4*)(r + ((size_t)b * Nr + base) * 3);
        float4* sv = (float4*)s;
        const int elems4 = C * 3 / 4;
        for (int t = threadIdx.x; t < elems4; t += BLK) sv[t] = gv[t];
    }
    __syncthreads();

    // load 4 query points (stride-BLK within the block's query window)
    float qx[QPT], qy[QPT], qz[QPT];
    int qi[QPT];
    bool qv[QPT];
#pragma unroll
    for (int k = 0; k < QPT; ++k) {
        qi[k] = blockIdx.x * QPB + k * BLK + threadIdx.x;
        qv[k] = qi[k] < Nq;
        const float* qp = q + ((size_t)b * Nq + (qv[k] ? qi[k] : 0)) * 3;
        qx[k] = qp[0]; qy[k] = qp[1]; qz[k] = qp[2];
    }

    // per-query running min + winning 8-group id
    float bd[QPT];
    int   gi[QPT];
#pragma unroll
    for (int k = 0; k < QPT; ++k) { bd[k] = INFINITY; gi[k] = 0; }

    const float4* sv = (const float4*)s;
    const int iters = C / 8;
    for (int j8 = 0; j8 < iters; ++j8) {
        // 24 floats = 8 ref points; all lanes same address -> LDS broadcast
        float4 f0 = sv[6 * j8 + 0];
        float4 f1 = sv[6 * j8 + 1];
        float4 f2 = sv[6 * j8 + 2];
        float4 f3 = sv[6 * j8 + 3];
        float4 f4 = sv[6 * j8 + 4];
        float4 f5 = sv[6 * j8 + 5];
        float px[8] = { f0.x, f0.w, f1.z, f2.y, f3.x, f3.w, f4.z, f5.y };
        float py[8] = { f0.y, f1.x, f1.w, f2.z, f3.y, f4.x, f4.w, f5.z };
        float pz[8] = { f0.z, f1.y, f2.x, f2.w, f3.z, f4.y, f5.x, f5.w };
#pragma unroll
        for (int k = 0; k < QPT; ++k) {
            float d[8];
#pragma unroll
            for (int p = 0; p < 8; ++p) {
                float dx = qx[k] - px[p];
                float dy = qy[k] - py[p];
                float dz = qz[k] - pz[p];
                d[p] = fmaf(dx, dx, fmaf(dy, dy, dz * dz));
            }
            // min-of-8 tree (compiler folds fminf pairs/triples into v_min3)
            float m01 = fminf(d[0], d[1]);
            float m23 = fminf(d[2], d[3]);
            float m45 = fminf(d[4], d[5]);
            float m67 = fminf(d[6], d[7]);
            float m = fminf(fminf(m01, m23), fminf(m45, m67));
            // strict < keeps the EARLIEST group attaining the min value
            if (m < bd[k]) { bd[k] = m; gi[k] = j8; }
        }
    }

    // resolve intra-group index of the winner by deterministic recompute
    // (same fmaf expression on the same LDS data -> bitwise identical d),
    // then fold into the global per-query slot via u64 atomicMin.
    const size_t obase = (size_t)(dir * B + b) * Nq;
#pragma unroll
    for (int k = 0; k < QPT; ++k) {
        if (!qv[k]) continue;
        const int g = gi[k];
        float4 f0 = sv[6 * g + 0];
        float4 f1 = sv[6 * g + 1];
        float4 f2 = sv[6 * g + 2];
        float4 f3 = sv[6 * g + 3];
        float4 f4 = sv[6 * g + 4];
        float4 f5 = sv[6 * g + 5];
        float px[8] = { f0.x, f0.w, f1.z, f2.y, f3.x, f3.w, f4.z, f5.y };
        float py[8] = { f0.y, f1.x, f1.w, f2.z, f3.y, f4.x, f4.w, f5.z };
        float pz[8] = { f0.z, f1.y, f2.x, f2.w, f3.z, f4.y, f5.x, f5.w };
        int best = 0;
#pragma unroll
        for (int p = 7; p >= 0; --p) {   // descending: ends at SMALLEST match
            float dx = qx[k] - px[p];
            float dy = qy[k] - py[p];
            float dz = qz[k] - pz[p];
            float d = fmaf(dx, dx, fmaf(dy, dy, dz * dz));
            if (d == bd[k]) best = p;    // match guaranteed (same bits)
        }
        const int idx = base + g * 8 + best;
        // d >= 0 -> float bits order-monotonic as unsigned.
        unsigned long long packed =
            ((unsigned long long)__float_as_uint(bd[k]) << 32) | (unsigned)idx;
        atomicMin(&pp[obase + qi[k]], packed);
    }
}

__global__ __launch_bounds__(256) void chamfer_final(
    const unsigned long long* __restrict__ pp,
    float* __restrict__ out, int N, int M, int B)
{
    const int gid = blockIdx.x * blockDim.x + threadIdx.x;
    const int perDir0 = B * N;
    int dir, rem;
    if (gid < perDir0) { dir = 0; rem = gid; }
    else if (gid < perDir0 + B * M) { dir = 1; rem = gid - perDir0; }
    else return;
    const int Nq = dir ? M : N;

    // pp is [2][B][Nq] flat; rem = b*Nq + i
    unsigned long long v = pp[(size_t)(dir * B) * Nq + rem];

    float* dist_out = out + (dir ? (size_t)B * N : 0);
    float* idx_out  = out + (size_t)B * N + (size_t)B * M + (dir ? (size_t)B * N : 0);
    dist_out[rem] = __uint_as_float((unsigned)(v >> 32));
    idx_out[rem]  = (float)(unsigned)(v & 0xffffffffu);
}

extern "C" void kernel_launch(void* const* d_in, const int* in_sizes, int n_in,
                              void* d_out, int out_size, void* d_ws, size_t ws_size,
                              hipStream_t stream) {
    const float* xyz1 = (const float*)d_in[0];
    const float* xyz2 = (const float*)d_in[1];
    float* out = (float*)d_out;
    const int B = 4;
    const int N = in_sizes[0] / (B * 3);
    const int M = in_sizes[1] / (B * 3);
    const int NQ = (N > M ? N : M);
    const int NR = (N > M ? N : M);

    int S = 32;
    while (NR % (S * 8)) S >>= 1;  // need C = NR/S divisible by 8
    const int C = NR / S;

    unsigned long long* pp = (unsigned long long*)d_ws;  // [2][B][NQ] packed slots
    const int nslots = 2 * B * NQ;

    // init pp to ~0ULL via byte-pattern memset (0xFF) — graph-capturable
    // memset node, replaces an init kernel (one fewer dispatch + gap).
    hipMemsetAsync(pp, 0xFF, (size_t)nslots * 8, stream);

    dim3 grid((NQ + QPB - 1) / QPB, B * S, 2);
    size_t lds = (size_t)C * 3 * sizeof(float);
    chamfer_main<<<grid, dim3(BLK, 1, 1), lds, stream>>>(
        xyz1, xyz2, pp, N, M, B, S, C);

    chamfer_final<<<dim3((nslots + 255) / 256, 1, 1), dim3(256, 1, 1), 0, stream>>>(
        pp, out, N, M, B);
}